// Round 4
// baseline (434.236 us; speedup 1.0000x reference)
//
#include <hip/hip_runtime.h>
#include <math.h>

#define D_G 5
#define N_G 100
#define IN_DIM 768
#define T_ROWS 100000
#define N_PAIRS (T_ROWS / 2)
#define LN_EPS 1e-5f

// ---------------------------------------------------------------------------
// Kernel A: per-gaussian precompute (inverse covariance folded + const term)
// ws layout: coeffs[k][16]: [0..4] diag(Minv), [5..14] 2*Minv[i][j] (i<j),
//            [15] = -0.5*(d*log(2pi) + logdet)
// ---------------------------------------------------------------------------
__global__ void precompute_gauss(const float* __restrict__ cov,
                                 float* __restrict__ coeffs) {
    int k = blockIdx.x * blockDim.x + threadIdx.x;
    if (k >= N_G) return;
    double a[D_G][D_G], inv[D_G][D_G];
    for (int i = 0; i < D_G; ++i)
        for (int j = 0; j < D_G; ++j) {
            a[i][j] = (double)cov[(k * D_G + i) * D_G + j];
            inv[i][j] = (i == j) ? 1.0 : 0.0;
        }
    double det = 1.0;
    for (int c = 0; c < D_G; ++c) {
        int p = c;
        double best = fabs(a[c][c]);
        for (int r = c + 1; r < D_G; ++r) {
            double v = fabs(a[r][c]);
            if (v > best) { best = v; p = r; }
        }
        if (p != c) {
            for (int j = 0; j < D_G; ++j) {
                double t = a[c][j]; a[c][j] = a[p][j]; a[p][j] = t;
                t = inv[c][j]; inv[c][j] = inv[p][j]; inv[p][j] = t;
            }
            det = -det;
        }
        double piv = a[c][c];
        det *= piv;
        double ip = 1.0 / piv;
        for (int j = 0; j < D_G; ++j) { a[c][j] *= ip; inv[c][j] *= ip; }
        for (int r = 0; r < D_G; ++r) {
            if (r == c) continue;
            double f = a[r][c];
            if (f != 0.0)
                for (int j = 0; j < D_G; ++j) {
                    a[r][j] -= f * a[c][j];
                    inv[r][j] -= f * inv[c][j];
                }
        }
    }
    double logdet = log(fabs(det));
    float* o = coeffs + k * 16;
    for (int i = 0; i < D_G; ++i) o[i] = (float)inv[i][i];
    int idx = D_G;
    for (int i = 0; i < D_G; ++i)
        for (int j = i + 1; j < D_G; ++j) o[idx++] = (float)(2.0 * inv[i][j]);
    o[15] = (float)(-0.5 * ((double)D_G * log(2.0 * 3.14159265358979323846) + logdet));
}

// ---------------------------------------------------------------------------
// Gaussian eval with folded symmetric coefficients
// ---------------------------------------------------------------------------
__device__ __forceinline__ float gm_eval(const float z[D_G], const float* ct,
                                         const float* cf, float cc) {
    float d0 = z[0] - ct[0];
    float d1 = z[1] - ct[1];
    float d2 = z[2] - ct[2];
    float d3 = z[3] - ct[3];
    float d4 = z[4] - ct[4];
    float m = cf[0] * (d0 * d0);
    m = fmaf(cf[1], d1 * d1, m);
    m = fmaf(cf[2], d2 * d2, m);
    m = fmaf(cf[3], d3 * d3, m);
    m = fmaf(cf[4], d4 * d4, m);
    m = fmaf(cf[5], d0 * d1, m);
    m = fmaf(cf[6], d0 * d2, m);
    m = fmaf(cf[7], d0 * d3, m);
    m = fmaf(cf[8], d0 * d4, m);
    m = fmaf(cf[9], d1 * d2, m);
    m = fmaf(cf[10], d1 * d3, m);
    m = fmaf(cf[11], d1 * d4, m);
    m = fmaf(cf[12], d2 * d3, m);
    m = fmaf(cf[13], d2 * d4, m);
    m = fmaf(cf[14], d3 * d4, m);
    return __expf(fmaf(-0.5f, m, cc));
}

__device__ __forceinline__ float dot12(const float4& xa, const float4& xb,
                                       const float4& xc, const float4& w0,
                                       const float4& w1, const float4& w2) {
    float s = xa.x * w0.x;
    s = fmaf(xa.y, w0.y, s);
    s = fmaf(xa.z, w0.z, s);
    s = fmaf(xa.w, w0.w, s);
    s = fmaf(xb.x, w1.x, s);
    s = fmaf(xb.y, w1.y, s);
    s = fmaf(xb.z, w1.z, s);
    s = fmaf(xb.w, w1.w, s);
    s = fmaf(xc.x, w2.x, s);
    s = fmaf(xc.y, w2.y, s);
    s = fmaf(xc.z, w2.z, s);
    s = fmaf(xc.w, w2.w, s);
    return s;
}

// ---------------------------------------------------------------------------
// Kernel B: main. One wave per PAIR of adjacent rows (2-row ILP: independent
// butterfly/exp chains interleave, halving exposed latency), with a 2-row
// deep prefetch (4 rows of loads in flight per wave).
// ---------------------------------------------------------------------------
__launch_bounds__(256, 2)
__global__ void gm_main(const float* __restrict__ x, const float* __restrict__ W,
                        const float* __restrict__ bb,
                        const float* __restrict__ centers,
                        const float* __restrict__ coeffs,
                        float* __restrict__ partials, int nblk) {
    const int lane = threadIdx.x & 63;
    const int wid = threadIdx.x >> 6;
    const int gw = blockIdx.x * 4 + wid;
    const int nw = nblk * 4;

    // W in registers: wreg[j][i] = W[j*768 + i*256 + lane*4 .. +3]
    float4 wreg[D_G][3];
#pragma unroll
    for (int j = 0; j < D_G; ++j)
#pragma unroll
        for (int i = 0; i < 3; ++i)
            wreg[j][i] = *reinterpret_cast<const float4*>(W + j * IN_DIM + i * 256 + lane * 4);

    float bj[D_G];
#pragma unroll
    for (int j = 0; j < D_G; ++j) bj[j] = bb[j];

    const int k0 = lane;                   // gaussians 0..63
    const bool has1 = lane < (N_G - 64);   // lanes 0..35 also own 64..99
    const int k1 = has1 ? (64 + lane) : lane;

    float cf0[15], cf1[15], ct0[D_G], ct1[D_G];
#pragma unroll
    for (int i = 0; i < 15; ++i) { cf0[i] = coeffs[k0 * 16 + i]; cf1[i] = coeffs[k1 * 16 + i]; }
#pragma unroll
    for (int i = 0; i < D_G; ++i) { ct0[i] = centers[k0 * D_G + i]; ct1[i] = centers[k1 * D_G + i]; }
    const float cc0 = coeffs[k0 * 16 + 15], cc1 = coeffs[k1 * 16 + 15];

    float acc0 = 0.f, acc1 = 0.f, accA = 0.f;

    int pr = gw;
    float4 A0{}, A1{}, A2{}, C0{}, C1{}, C2{};
    if (pr < N_PAIRS) {
        const float* xr = x + (size_t)(2 * pr) * IN_DIM + lane * 4;
        A0 = *reinterpret_cast<const float4*>(xr);
        A1 = *reinterpret_cast<const float4*>(xr + 256);
        A2 = *reinterpret_cast<const float4*>(xr + 512);
        C0 = *reinterpret_cast<const float4*>(xr + 768);
        C1 = *reinterpret_cast<const float4*>(xr + 1024);
        C2 = *reinterpret_cast<const float4*>(xr + 1280);
    }

    while (pr < N_PAIRS) {
        const int pn = pr + nw;
        float4 B0{}, B1{}, B2{}, D0{}, D1{}, D2{};
        if (pn < N_PAIRS) {  // prefetch next pair before the dependency chains
            const float* xr = x + (size_t)(2 * pn) * IN_DIM + lane * 4;
            B0 = *reinterpret_cast<const float4*>(xr);
            B1 = *reinterpret_cast<const float4*>(xr + 256);
            B2 = *reinterpret_cast<const float4*>(xr + 512);
            D0 = *reinterpret_cast<const float4*>(xr + 768);
            D1 = *reinterpret_cast<const float4*>(xr + 1024);
            D2 = *reinterpret_cast<const float4*>(xr + 1280);
        }

        float pA[D_G], pB[D_G];
#pragma unroll
        for (int j = 0; j < D_G; ++j) {
            pA[j] = dot12(A0, A1, A2, wreg[j][0], wreg[j][1], wreg[j][2]);
            pB[j] = dot12(C0, C1, C2, wreg[j][0], wreg[j][1], wreg[j][2]);
        }
        // interleaved wave-wide butterflies: 10 independent chains
#pragma unroll
        for (int m = 32; m >= 1; m >>= 1) {
#pragma unroll
            for (int j = 0; j < D_G; ++j) {
                pA[j] += __shfl_xor(pA[j], m, 64);
                pB[j] += __shfl_xor(pB[j], m, 64);
            }
        }
        float zA[D_G], zB[D_G];
#pragma unroll
        for (int j = 0; j < D_G; ++j) {
            zA[j] = __builtin_amdgcn_rcpf(1.0f + __expf(-(pA[j] + bj[j])));
            zB[j] = __builtin_amdgcn_rcpf(1.0f + __expf(-(pB[j] + bj[j])));
        }

        const float likA0 = gm_eval(zA, ct0, cf0, cc0);
        const float eA1 = gm_eval(zA, ct1, cf1, cc1);
        const float likA1 = has1 ? eA1 : 0.f;
        const float likB0 = gm_eval(zB, ct0, cf0, cc0);
        const float eB1 = gm_eval(zB, ct1, cf1, cc1);
        const float likB1 = has1 ? eB1 : 0.f;

        float sA = likA0 + likA1;
        float qA = fmaf(likA0, likA0, likA1 * likA1);
        float sB = likB0 + likB1;
        float qB = fmaf(likB0, likB0, likB1 * likB1);
#pragma unroll
        for (int m = 32; m >= 1; m >>= 1) {
            sA += __shfl_xor(sA, m, 64);
            qA += __shfl_xor(qA, m, 64);
            sB += __shfl_xor(sB, m, 64);
            qB += __shfl_xor(qB, m, 64);
        }
        const float muA = sA * (1.0f / N_G);
        float varA = fmaf(qA, 1.0f / N_G, -muA * muA);
        varA = fmaxf(varA, 0.f);
        const float rA = rsqrtf(varA + LN_EPS);
        const float muB = sB * (1.0f / N_G);
        float varB = fmaf(qB, 1.0f / N_G, -muB * muB);
        varB = fmaxf(varB, 0.f);
        const float rB = rsqrtf(varB + LN_EPS);

        acc0 = fmaf(likA0, rA, fmaf(likB0, rB, acc0));
        acc1 = fmaf(likA1, rA, fmaf(likB1, rB, acc1));
        accA = fmaf(muA, rA, fmaf(muB, rB, accA));

        A0 = B0; A1 = B1; A2 = B2;
        C0 = D0; C1 = D1; C2 = D2;
        pr = pn;
    }

    __shared__ float sacc[N_G + 1];
    if (threadIdx.x < N_G + 1) sacc[threadIdx.x] = 0.f;
    __syncthreads();
    atomicAdd(&sacc[k0], acc0);
    if (has1) atomicAdd(&sacc[k1], acc1);
    if (lane == 0) atomicAdd(&sacc[N_G], accA);
    __syncthreads();
    if (threadIdx.x < N_G + 1)
        partials[(size_t)threadIdx.x * nblk + blockIdx.x] = sacc[threadIdx.x];
}

// ---------------------------------------------------------------------------
// Kernel C: reduce per-block partials -> out[k] (double accumulation),
// applying LayerNorm affine: out_k = gamma_k*(S_k - A)/T + beta_k
// ---------------------------------------------------------------------------
__global__ void reduce_partials(const float* __restrict__ partials,
                                const float* __restrict__ gamma_,
                                const float* __restrict__ beta_,
                                float* __restrict__ out, int nblk) {
    const int k = blockIdx.x;
    const int lane = threadIdx.x & 63;
    const int wid = threadIdx.x >> 6;
    double dk = 0.0, dA = 0.0;
    for (int b = threadIdx.x; b < nblk; b += blockDim.x) {
        dk += (double)partials[(size_t)k * nblk + b];
        dA += (double)partials[(size_t)N_G * nblk + b];
    }
#pragma unroll
    for (int m = 32; m >= 1; m >>= 1) {
        dk += __shfl_xor(dk, m, 64);
        dA += __shfl_xor(dA, m, 64);
    }
    __shared__ double sk[4], sA[4];
    if (lane == 0) { sk[wid] = dk; sA[wid] = dA; }
    __syncthreads();
    if (threadIdx.x == 0) {
        double S = sk[0] + sk[1] + sk[2] + sk[3];
        double A = sA[0] + sA[1] + sA[2] + sA[3];
        out[k] = (float)((double)gamma_[k] * (S - A) * (1.0 / (double)T_ROWS)
                         + (double)beta_[k]);
    }
}

extern "C" void kernel_launch(void* const* d_in, const int* in_sizes, int n_in,
                              void* d_out, int out_size, void* d_ws, size_t ws_size,
                              hipStream_t stream) {
    const float* x = (const float*)d_in[0];
    const float* W = (const float*)d_in[1];
    const float* b = (const float*)d_in[2];
    const float* centers = (const float*)d_in[3];
    const float* cov = (const float*)d_in[4];
    const float* gamma_ = (const float*)d_in[5];
    const float* beta_ = (const float*)d_in[6];
    float* out = (float*)d_out;

    float* ws = (float*)d_ws;
    float* coeffs = ws;                 // N_G * 16 floats
    float* partials = ws + N_G * 16;    // (N_G+1) * nblk floats

    // 512 blocks = 2 blocks/CU guaranteed resident (launch_bounds(256,2))
    int nblk = 512;
    {
        long avail = (long)(ws_size / sizeof(float)) - (long)(N_G * 16);
        long maxblk = avail / (N_G + 1);
        if (maxblk < nblk) nblk = (int)maxblk;
        if (nblk < 1) nblk = 1;
    }

    precompute_gauss<<<1, 128, 0, stream>>>(cov, coeffs);
    gm_main<<<nblk, 256, 0, stream>>>(x, W, b, centers, coeffs, partials, nblk);
    reduce_partials<<<N_G, 256, 0, stream>>>(partials, gamma_, beta_, out, nblk);
}